// Round 10
// baseline (363.318 us; speedup 1.0000x reference)
//
#include <hip/hip_runtime.h>
#include <hip/hip_bf16.h>
#include <math.h>

#define NPART 16  // s-blocks of 256: 64x16 = 1024 blocks

typedef __attribute__((ext_vector_type(8))) short bf16x8;  // MFMA A/B frag (4 VGPR)
typedef __attribute__((ext_vector_type(4))) float f32x4;   // MFMA C/D frag

static __device__ inline ushort f2bf(float x) {
  __hip_bfloat16 h = __float2bfloat16(x);
  return *reinterpret_cast<ushort*>(&h);
}

// ---------------------------------------------------------------------------
// Elementwise cast f32 -> bf16 (n multiple of 4)
// ---------------------------------------------------------------------------
__global__ __launch_bounds__(256) void cast_bf16_kernel(
    const float* __restrict__ in, ushort* __restrict__ out, size_t n4) {
  size_t i = (size_t)blockIdx.x * blockDim.x + threadIdx.x;
  size_t stride = (size_t)gridDim.x * blockDim.x;
  for (; i < n4; i += stride) {
    float4 v = ((const float4*)in)[i];
    ushort4 u;
    u.x = f2bf(v.x); u.y = f2bf(v.y); u.z = f2bf(v.z); u.w = f2bf(v.w);
    ((ushort4*)out)[i] = u;
  }
}

// ---------------------------------------------------------------------------
// Transpose-cast W[K][D] f32 -> Wt[D][K] bf16 (64x64 LDS tiles)
// ---------------------------------------------------------------------------
__global__ __launch_bounds__(256) void transpose_cast_kernel(
    const float* __restrict__ W, ushort* __restrict__ Wt, int K, int D) {
  __shared__ float t[64][65];
  const int k0 = blockIdx.x * 64, d0 = blockIdx.y * 64;
  const int r = threadIdx.x >> 6, c = threadIdx.x & 63;
#pragma unroll
  for (int i = 0; i < 16; i++)
    t[r + i * 4][c] = W[(size_t)(k0 + r + i * 4) * D + d0 + c];
  __syncthreads();
#pragma unroll
  for (int i = 0; i < 16; i++)
    Wt[(size_t)(d0 + r + i * 4) * K + k0 + c] = f2bf(t[c][r + i * 4]);
}

// ---------------------------------------------------------------------------
// Encoder MFMA GEMM (unchanged this round): emb = Xb @ Wt^T + b
// ---------------------------------------------------------------------------
__global__ __launch_bounds__(256) void encode_mfma_kernel(
    const ushort* __restrict__ Xb, const ushort* __restrict__ Wt,
    const float* __restrict__ bias, float* __restrict__ emb,
    int K, int D) {
  const int tid = threadIdx.x;
  const int wave = tid >> 6, lane = tid & 63;
  const int fr = lane & 15, kg = lane >> 4;
  const long row0 = (long)blockIdx.x * 64, col0 = (long)blockIdx.y * 64;

  f32x4 acc[4];
#pragma unroll
  for (int c = 0; c < 4; c++) acc[c] = (f32x4){0.f, 0.f, 0.f, 0.f};

  const ushort* xrow = Xb + (row0 + wave * 16 + fr) * (size_t)K;
  const int nt = K / 32;
  for (int t = 0; t < nt; t++) {
    bf16x8 af = *(const bf16x8*)(xrow + t * 32 + kg * 8);
#pragma unroll
    for (int c = 0; c < 4; c++) {
      const ushort* wrow = Wt + (col0 + c * 16 + fr) * (size_t)K;
      bf16x8 bf = *(const bf16x8*)(wrow + t * 32 + kg * 8);
      acc[c] = __builtin_amdgcn_mfma_f32_16x16x32_bf16(af, bf, acc[c], 0, 0, 0);
    }
  }
#pragma unroll
  for (int c = 0; c < 4; c++) {
    float bl = bias[col0 + c * 16 + fr];
#pragma unroll
    for (int r = 0; r < 4; r++)
      emb[(row0 + wave * 16 + kg * 4 + r) * (size_t)D + col0 + c * 16 + fr] =
          acc[c][r] + bl;
  }
}

// ---------------------------------------------------------------------------
// Row L2-normalize fp32 -> bf16 (one wave per row, D = 512)
// ---------------------------------------------------------------------------
__global__ __launch_bounds__(256) void norm_bf16_kernel(
    const float* __restrict__ in, ushort* __restrict__ outb, int nrows, int D) {
  int row = (int)((blockIdx.x * blockDim.x + threadIdx.x) >> 6);
  int lane = threadIdx.x & 63;
  if (row >= nrows) return;
  const float4* p = (const float4*)(in + (size_t)row * D);
  float4 v0 = p[lane];
  float4 v1 = p[lane + 64];
  float ss = v0.x * v0.x + v0.y * v0.y + v0.z * v0.z + v0.w * v0.w
           + v1.x * v1.x + v1.y * v1.y + v1.z * v1.z + v1.w * v1.w;
#pragma unroll
  for (int off = 32; off > 0; off >>= 1) ss += __shfl_xor(ss, off);
  float inv = 1.0f / fmaxf(sqrtf(ss), 1e-12f);
  ushort4 u0, u1;
  u0.x = f2bf(v0.x * inv); u0.y = f2bf(v0.y * inv);
  u0.z = f2bf(v0.z * inv); u0.w = f2bf(v0.w * inv);
  u1.x = f2bf(v1.x * inv); u1.y = f2bf(v1.y * inv);
  u1.z = f2bf(v1.z * inv); u1.w = f2bf(v1.w * inv);
  ushort* o = outb + (size_t)row * D;
  *(ushort4*)(o + 4 * lane) = u0;
  *(ushort4*)(o + 256 + 4 * lane) = u1;
}

// ---------------------------------------------------------------------------
// MFMA attention — T3 minimum-2-phase pipeline (double-buffered staging,
// counted-wait, 1 barrier/phase):
//   STAGE(0)
//   for t: vmcnt(0) [stage(t) landed, hidden under compute(t-1)];
//          raw s_barrier [no implicit drain];
//          STAGE(t+1) -> other buffer;  compute(t): 8 ds_read + 16 MFMA
// LDS tile restored to r7's FRAGMENT-ORDER layout (0 bank conflicts):
// seg s (0-7 Q rowgroups, 8-23 S rowgroups), slot = lane*16B; per-lane
// global src is the fragment source (rule #21 pattern, r6/r7-proven).
// Buckets OVERLAY the tile region (epilogue-only use) -> LDS ~50 KB.
// Race audit: stage(t+1) targets buf read at t-1, whose ds_reads completed
// before each wave's barrier(t) signal (MFMA consumption forces them).
// ---------------------------------------------------------------------------
__global__ __launch_bounds__(512, 4) void attn_mfma_kernel(
    const ushort* __restrict__ Qb, const ushort* __restrict__ Sb,
    const int* __restrict__ labels, float* __restrict__ partial,
    int nq, int D) {
  __shared__ ushort tile[2 * 12288];   // 2 x 24 KB double buffer
  __shared__ int lab[256];
  float* buckets = (float*)tile;       // overlay: 128*65*4 = 33280 B < 49152 B
  const int tid = threadIdx.x;
  const int wave = tid >> 6, lane = tid & 63;
  const int fr = lane & 15, kg = lane >> 4;
  const int wr = wave >> 2, wc = wave & 3;   // 2x4 wave grid
  const long q0 = (long)blockIdx.x * 128;
  const int part = blockIdx.y;
  const long s0 = (long)part * 256;

  f32x4 acc[4][4];
#pragma unroll
  for (int rg = 0; rg < 4; rg++)
#pragma unroll
    for (int cg = 0; cg < 4; cg++) acc[rg][cg] = (f32x4){0.f, 0.f, 0.f, 0.f};

#define STAGE(kt, pb)                                                         \
  {                                                                           \
    _Pragma("unroll")                                                         \
    for (int i_ = 0; i_ < 3; i_++) {                                          \
      const int seg_ = wave * 3 + i_;                                         \
      const ushort* src_ = (seg_ < 8)                                         \
          ? Qb + (q0 + seg_ * 16 + fr) * (size_t)D + (kt) * 32 + kg * 8       \
          : Sb + (s0 + (seg_ - 8) * 16 + fr) * (size_t)D + (kt) * 32 + kg * 8;\
      __builtin_amdgcn_global_load_lds(                                       \
          (const __attribute__((address_space(1))) void*)src_,                \
          (__attribute__((address_space(3))) void*)                           \
              &tile[(pb) * 12288 + seg_ * 512 + lane * 8],                    \
          16, 0, 0);                                                          \
    }                                                                         \
  }

  STAGE(0, 0)
  for (int t = 0; t < 16; t++) {       // K = 512 = 16 x BK(32)
    const int p = t & 1;
    asm volatile("s_waitcnt vmcnt(0)" ::: "memory");  // own stage(t) landed
    __builtin_amdgcn_sched_barrier(0);                // rule #18 fence
    __builtin_amdgcn_s_barrier();                     // all stage(t) landed
    if (t < 15) STAGE(t + 1, p ^ 1)                   // prefetch next tile
    const ushort* base = &tile[p * 12288];
    bf16x8 bfr[4];
#pragma unroll
    for (int cg = 0; cg < 4; cg++)
      bfr[cg] = *(const bf16x8*)&base[(8 + wc * 4 + cg) * 512 + lane * 8];
#pragma unroll
    for (int rg = 0; rg < 4; rg++) {
      bf16x8 af = *(const bf16x8*)&base[(wr * 4 + rg) * 512 + lane * 8];
#pragma unroll
      for (int cg = 0; cg < 4; cg++)
        acc[rg][cg] = __builtin_amdgcn_mfma_f32_16x16x32_bf16(
            af, bfr[cg], acc[rg][cg], 0, 0, 0);
    }
  }
#undef STAGE

  // ---- epilogue: overlay buckets onto tile region ----
  __syncthreads();                     // all tile reads done before overlay
  for (int i = tid; i < 128 * 65; i += 512) buckets[i] = 0.0f;
  if (tid < 256) lab[tid] = labels[s0 + tid];
  __syncthreads();
  // acc[rg][cg][r] = score(q0+wr*64+rg*16+kg*4+r, s0+wc*64+cg*16+fr)
#pragma unroll
  for (int cg = 0; cg < 4; cg++) {
    int lb = lab[wc * 64 + cg * 16 + fr];
#pragma unroll
    for (int rg = 0; rg < 4; rg++)
#pragma unroll
      for (int r = 0; r < 4; r++)
        atomicAdd(&buckets[(wr * 64 + rg * 16 + kg * 4 + r) * 65 + lb],
                  __expf(acc[rg][cg][r]));
  }
  __syncthreads();
  for (int i = tid; i < 128 * 64; i += 512) {
    int q = i >> 6, c = i & 63;
    partial[((size_t)part * nq + (q0 + q)) * 64 + c] = buckets[q * 65 + c];
  }
}

// ---------------------------------------------------------------------------
// Combine: sum partials over splits; denominator = row-sum of buckets
// ---------------------------------------------------------------------------
__global__ __launch_bounds__(256) void combine_kernel(
    const float* __restrict__ partial, float* __restrict__ out, int nq, int nsplit) {
  int q = (int)((blockIdx.x * blockDim.x + threadIdx.x) >> 6);
  int lane = threadIdx.x & 63;
  if (q >= nq) return;
  float v = 0.0f;
  for (int h = 0; h < nsplit; h++)
    v += partial[((size_t)h * nq + q) * 64 + lane];
  float s = v;
#pragma unroll
  for (int off = 32; off > 0; off >>= 1) s += __shfl_xor(s, off);
  out[(size_t)q * 64 + lane] = v / s;
}

// ---------------------------------------------------------------------------
// Workspace layout (peak 49 MB; aliases only reuse dead buffers):
//  [0,8M) xb_s  [8M,24M) xb_q  [24M,25M) Wt  [25M,33M) s_emb  [33M,49M) q_emb
//  after encode+norm: s_bf [0,4M), q_bf [4M,12M), partial [12M,44M) (32 MB)
// ---------------------------------------------------------------------------
extern "C" void kernel_launch(void* const* d_in, const int* in_sizes, int n_in,
                              void* d_out, int out_size, void* d_ws, size_t ws_size,
                              hipStream_t stream) {
  const float* support = (const float*)d_in[0];
  const float* query   = (const float*)d_in[1];
  const float* W       = (const float*)d_in[2];
  const float* b       = (const float*)d_in[3];
  const int*   labels  = (const int*)d_in[4];

  const int d_dim    = in_sizes[3];            // 512
  const int in_dim   = in_sizes[2] / d_dim;    // 1024
  const int n_support = in_sizes[0] / in_dim;  // 4096
  const int n_query   = in_sizes[1] / in_dim;  // 8192

  char* base = (char*)d_ws;
  ushort* xb_s  = (ushort*)(base);
  ushort* xb_q  = (ushort*)(base + ((size_t)8 << 20));
  ushort* Wt    = (ushort*)(base + ((size_t)24 << 20));
  float*  s_emb = (float*)(base + ((size_t)25 << 20));
  float*  q_emb = (float*)(base + ((size_t)33 << 20));
  ushort* s_bf  = (ushort*)(base);                        // alias xb_s (dead)
  ushort* q_bf  = (ushort*)(base + ((size_t)4 << 20));    // alias xb (dead)
  float*  partial = (float*)(base + ((size_t)12 << 20));  // alias xb/Wt/emb (dead)

  dim3 blk(256);
  cast_bf16_kernel<<<2048, blk, 0, stream>>>(support, xb_s, (size_t)n_support * in_dim / 4);
  cast_bf16_kernel<<<2048, blk, 0, stream>>>(query, xb_q, (size_t)n_query * in_dim / 4);
  transpose_cast_kernel<<<dim3(in_dim / 64, d_dim / 64), blk, 0, stream>>>(W, Wt, in_dim, d_dim);
  encode_mfma_kernel<<<dim3(n_support / 64, d_dim / 64), blk, 0, stream>>>(
      xb_s, Wt, b, s_emb, in_dim, d_dim);
  encode_mfma_kernel<<<dim3(n_query / 64, d_dim / 64), blk, 0, stream>>>(
      xb_q, Wt, b, q_emb, in_dim, d_dim);
  norm_bf16_kernel<<<dim3(n_support / 4), blk, 0, stream>>>(s_emb, s_bf, n_support, d_dim);
  norm_bf16_kernel<<<dim3(n_query / 4), blk, 0, stream>>>(q_emb, q_bf, n_query, d_dim);
  attn_mfma_kernel<<<dim3(n_query / 128, NPART), dim3(512), 0, stream>>>(
      q_bf, s_bf, labels, partial, n_query, d_dim);
  combine_kernel<<<dim3(n_query / 4), blk, 0, stream>>>(partial, (float*)d_out, n_query, NPART);
}